// Round 3
// baseline (3001.250 us; speedup 1.0000x reference)
//
#include <hip/hip_runtime.h>
#include <math.h>

#define HID 256
#define G3 768
#define DIM 128
#define TW 50
#define NSENT 2048
#define NDOC 64
#define LSENT 32
#define PDOC 50
#define PSENT 100
#define PDIMM 50

// workspace offsets (in floats)
static constexpr long OFF_W4_wWi_f = 0;
static constexpr long OFF_W4_wWi_b = 98304;
static constexpr long OFF_W4_wWh_f = 196608;
static constexpr long OFF_W4_wWh_b = 393216;
static constexpr long OFF_W4_sWi_f = 589824;
static constexpr long OFF_W4_sWi_b = 983040;
static constexpr long OFF_W4_sWh_f = 1376256;
static constexpr long OFF_W4_sWh_b = 1572864;
static constexpr long OFF_W4_dWi_f = 1769472;
static constexpr long OFF_W4_dWi_b = 2162688;
static constexpr long OFF_W4_dWh_f = 2555904;
static constexpr long OFF_W4_dWh_b = 2752512;
static constexpr long OFF_W4_salT  = 2949120;
static constexpr long OFF_LENS     = 3473408;
static constexpr long OFF_SENTVEC  = 3475456;   // [2048,512]
static constexpr long OFF_XGS      = 4524032;   // [2048,1536]
static constexpr long OFF_DOCVEC   = 7669760;   // [64,512]
static constexpr long OFF_XGD      = 7702528;   // [64,1536]
static constexpr long OFF_BLOG     = 7800832;   // [512]

__device__ __forceinline__ float sigm(float v){ return 1.0f/(1.0f+__expf(-v)); }
__device__ __forceinline__ float tanhfast(float v){ return 1.0f - 2.0f/(1.0f+__expf(2.0f*v)); }

__device__ __forceinline__ void fma4(float& acc, const float4 a, const float4 b){
  acc = fmaf(a.x, b.x, fmaf(a.y, b.y, fmaf(a.z, b.z, fmaf(a.w, b.w, acc))));
}

struct TD { const float* src; long dst; long cnt; int sh; int R; };
struct TT { TD t[13]; };

// packed-4 transpose: dst[((col>>2)*R + j)*4 + (col&3)] = src[j*Dk + col]
__global__ __launch_bounds__(256) void k_transpose(TT tt, float* __restrict__ ws, long total){
  long g = (long)blockIdx.x*256 + threadIdx.x;
  if (g >= total) return;
  int k = 0; long r = g;
  while (r >= tt.t[k].cnt) { r -= tt.t[k].cnt; ++k; }
  const float* src = tt.t[k].src;
  int sh = tt.t[k].sh; int R = tt.t[k].R;
  long j = r >> sh;
  int col = (int)(r & ((1L<<sh)-1));
  ws[tt.t[k].dst + (((long)(col>>2))*R + j)*4 + (col&3)] = src[r];
}

__global__ __launch_bounds__(256) void k_lens(const int* __restrict__ x, int* __restrict__ lens){
  int n = blockIdx.x*256 + threadIdx.x;
  if (n >= NSENT) return;
  int c = 0;
  for (int t = 0; t < TW; ++t) c += (x[n*TW + t] != 0) ? 1 : 0;
  lens[n] = c;
}

// ---------------- word-level BiGRU (fused gather + input gates + recurrence + masked max) -------------
// grid 256: blk -> dir=blk&1, 16 sentences; 512 threads = 2 teams x 256, each team 8 sentences
__global__ __launch_bounds__(512)
void k_word(const int* __restrict__ x, const float* __restrict__ embed,
            const float* __restrict__ W4i_f, const float* __restrict__ W4i_b,
            const float* __restrict__ W4h_f, const float* __restrict__ W4h_b,
            const float* __restrict__ bi_f, const float* __restrict__ bi_b,
            const float* __restrict__ bh_f, const float* __restrict__ bh_b,
            const int* __restrict__ lens, float* __restrict__ sent_vec)
{
  __shared__ __align__(16) float h_lds[16][HID];
  __shared__ __align__(16) float e_lds[16][DIM];
  const int blk = blockIdx.x;
  const int dir = blk & 1;
  const int n0  = (blk >> 1) * 16;
  const int tid = threadIdx.x;
  const int team = tid >> 8;
  const int j   = tid & 255;
  const int m0  = team * 8;
  const float* W4i = dir ? W4i_b : W4i_f;
  const float* W4h = dir ? W4h_b : W4h_f;
  const float* bi  = dir ? bi_b  : bi_f;
  const float* bh  = dir ? bh_b  : bh_f;
  const float b_r  = bi[j]       + bh[j];
  const float b_z  = bi[j+HID]   + bh[j+HID];
  const float b_nx = bi[j+2*HID];
  const float b_nh = bh[j+2*HID];
  int len_[8];
  #pragma unroll
  for (int mm = 0; mm < 8; ++mm) len_[mm] = lens[n0 + m0 + mm];
  for (int i = tid; i < 16*HID; i += 512) ((float*)h_lds)[i] = 0.0f;
  float rmax[8];
  #pragma unroll
  for (int mm = 0; mm < 8; ++mm) rmax[mm] = -INFINITY;
  const int msel = tid >> 5;           // 0..15
  const int ccol = (tid & 31) * 4;     // 0..124
  __syncthreads();

  for (int t = 0; t < TW; ++t) {
    const int t_x = dir ? (TW-1-t) : t;
    // gather embeddings for this step (embed row 0 is zeros per setup)
    {
      int tok = x[(n0 + msel)*TW + t_x];
      float4 ev = *(const float4*)(embed + (long)tok*DIM + ccol);
      *(float4*)(&e_lds[msel][ccol]) = ev;
    }
    __syncthreads();

    float a_r[8], a_z[8], a_nx[8], a_nh[8];
    #pragma unroll
    for (int mm = 0; mm < 8; ++mm){ a_r[mm]=b_r; a_z[mm]=b_z; a_nx[mm]=b_nx; a_nh[mm]=b_nh; }

    // input gates: Din = 128
    for (int d4 = 0; d4 < DIM/4; ++d4) {
      const float4 wr = *(const float4*)(W4i + ((long)d4*G3 + j        )*4);
      const float4 wz = *(const float4*)(W4i + ((long)d4*G3 + j +   HID)*4);
      const float4 wn = *(const float4*)(W4i + ((long)d4*G3 + j + 2*HID)*4);
      #pragma unroll
      for (int mm = 0; mm < 8; ++mm){
        const float4 e4 = *(const float4*)(&e_lds[m0+mm][d4*4]);
        fma4(a_r[mm],  wr, e4);
        fma4(a_z[mm],  wz, e4);
        fma4(a_nx[mm], wn, e4);
      }
    }
    // recurrent gates: H = 256
    for (int d4 = 0; d4 < HID/4; ++d4) {
      const float4 wr = *(const float4*)(W4h + ((long)d4*G3 + j        )*4);
      const float4 wz = *(const float4*)(W4h + ((long)d4*G3 + j +   HID)*4);
      const float4 wn = *(const float4*)(W4h + ((long)d4*G3 + j + 2*HID)*4);
      #pragma unroll
      for (int mm = 0; mm < 8; ++mm){
        const float4 h4 = *(const float4*)(&h_lds[m0+mm][d4*4]);
        fma4(a_r[mm],  wr, h4);
        fma4(a_z[mm],  wz, h4);
        fma4(a_nh[mm], wn, h4);
      }
    }
    float hnew[8];
    #pragma unroll
    for (int mm = 0; mm < 8; ++mm){
      float rg = sigm(a_r[mm]);
      float zg = sigm(a_z[mm]);
      float ng = tanhfast(a_nx[mm] + rg*a_nh[mm]);
      float hold = h_lds[m0+mm][j];
      float hv = (1.0f - zg)*ng + zg*hold;
      hnew[mm] = hv;
      bool inm = dir ? (t >= TW - len_[mm]) : (t < len_[mm]);
      if (inm) rmax[mm] = fmaxf(rmax[mm], hv);
    }
    __syncthreads();
    #pragma unroll
    for (int mm = 0; mm < 8; ++mm) h_lds[m0+mm][j] = hnew[mm];
    __syncthreads();
  }
  #pragma unroll
  for (int mm = 0; mm < 8; ++mm){
    float v = (len_[mm] > 0) ? rmax[mm] : 0.0f;
    sent_vec[(long)(n0+m0+mm)*(2*HID) + dir*HID + j] = v;
  }
}

// ---------------- input-gate GEMM: out[b, 0:768]=fwd gates, [768:1536]=bwd; Din=512 ----------------
__global__ __launch_bounds__(256)
void k_gates(const float* __restrict__ A,
             const float* __restrict__ W4f, const float* __restrict__ W4b,
             const float* __restrict__ bif, const float* __restrict__ bib,
             float* __restrict__ out)
{
  __shared__ __align__(16) float a_lds[8][512];
  const int r0 = blockIdx.x * 8;
  const int j  = threadIdx.x;
  #pragma unroll
  for (int q = 0; q < 4; ++q) {
    int fi = j + q*256;
    int rr = fi >> 7; int cc = (fi & 127) * 4;
    *(float4*)(&a_lds[rr][cc]) = *(const float4*)(A + (long)(r0+rr)*512 + cc);
  }
  __syncthreads();
  float acc[6][8];
  {
    float bias[6] = { bif[j], bif[j+256], bif[j+512], bib[j], bib[j+256], bib[j+512] };
    #pragma unroll
    for (int k = 0; k < 6; ++k)
      #pragma unroll
      for (int rr = 0; rr < 8; ++rr) acc[k][rr] = bias[k];
  }
  for (int d4 = 0; d4 < 128; ++d4) {
    float4 w0 = *(const float4*)(W4f + ((long)d4*G3 + j      )*4);
    float4 w1 = *(const float4*)(W4f + ((long)d4*G3 + j + 256)*4);
    float4 w2 = *(const float4*)(W4f + ((long)d4*G3 + j + 512)*4);
    float4 w3 = *(const float4*)(W4b + ((long)d4*G3 + j      )*4);
    float4 w4v= *(const float4*)(W4b + ((long)d4*G3 + j + 256)*4);
    float4 w5 = *(const float4*)(W4b + ((long)d4*G3 + j + 512)*4);
    #pragma unroll
    for (int rr = 0; rr < 8; ++rr){
      const float4 a4 = *(const float4*)(&a_lds[rr][d4*4]);
      fma4(acc[0][rr], w0, a4);
      fma4(acc[1][rr], w1, a4);
      fma4(acc[2][rr], w2, a4);
      fma4(acc[3][rr], w3, a4);
      fma4(acc[4][rr], w4v, a4);
      fma4(acc[5][rr], w5, a4);
    }
  }
  #pragma unroll
  for (int rr = 0; rr < 8; ++rr){
    long base = (long)(r0+rr)*1536;
    out[base + j      ] = acc[0][rr];
    out[base + j + 256] = acc[1][rr];
    out[base + j + 512] = acc[2][rr];
    out[base + j + 768] = acc[3][rr];
    out[base + j +1024] = acc[4][rr];
    out[base + j +1280] = acc[5][rr];
  }
}

// ---------------- sentence-level BiGRU recurrence (xg precomputed); 2 docs per block ----------------
__global__ __launch_bounds__(256)
void k_sent(const float* __restrict__ xg,
            const float* __restrict__ W4h_f, const float* __restrict__ W4h_b,
            const float* __restrict__ bh_f, const float* __restrict__ bh_b,
            const int* __restrict__ dlens, float* __restrict__ doc_vec)
{
  __shared__ __align__(16) float h_lds[2][HID];
  const int blk = blockIdx.x;
  const int dir = blk & 1;
  const int d0  = (blk >> 1) * 2;
  const int j   = threadIdx.x;
  const float* W4h = dir ? W4h_b : W4h_f;
  const float* bh  = dir ? bh_b  : bh_f;
  const float bhr = bh[j], bhz = bh[j+256], bhn = bh[j+512];
  const int lenA = dlens[d0], lenB = dlens[d0+1];
  h_lds[0][j] = 0.0f; h_lds[1][j] = 0.0f;
  float rmaxA = -INFINITY, rmaxB = -INFINITY;
  __syncthreads();
  for (int t = 0; t < LSENT; ++t) {
    const int row = dir ? (LSENT-1-t) : t;
    const float* xga = xg + ((long)(d0*LSENT + row))*1536 + dir*768;
    const float* xgb = xg + ((long)((d0+1)*LSENT + row))*1536 + dir*768;
    const float xrA = xga[j], xzA = xga[j+256], xnA = xga[j+512];
    const float xrB = xgb[j], xzB = xgb[j+256], xnB = xgb[j+512];
    float arA=bhr, azA=bhz, anA=bhn, arB=bhr, azB=bhz, anB=bhn;
    for (int d4 = 0; d4 < HID/4; ++d4) {
      const float4 wr = *(const float4*)(W4h + ((long)d4*G3 + j      )*4);
      const float4 wz = *(const float4*)(W4h + ((long)d4*G3 + j + 256)*4);
      const float4 wn = *(const float4*)(W4h + ((long)d4*G3 + j + 512)*4);
      const float4 hA = *(const float4*)(&h_lds[0][d4*4]);
      const float4 hB = *(const float4*)(&h_lds[1][d4*4]);
      fma4(arA, wr, hA); fma4(azA, wz, hA); fma4(anA, wn, hA);
      fma4(arB, wr, hB); fma4(azB, wz, hB); fma4(anB, wn, hB);
    }
    float rA = sigm(xrA + arA), zA = sigm(xzA + azA);
    float nA = tanhfast(xnA + rA*anA);
    float hAn = (1.0f - zA)*nA + zA*h_lds[0][j];
    float rB = sigm(xrB + arB), zB = sigm(xzB + azB);
    float nB = tanhfast(xnB + rB*anB);
    float hBn = (1.0f - zB)*nB + zB*h_lds[1][j];
    bool mA = dir ? (t >= LSENT - lenA) : (t < lenA);
    bool mB = dir ? (t >= LSENT - lenB) : (t < lenB);
    if (mA) rmaxA = fmaxf(rmaxA, hAn);
    if (mB) rmaxB = fmaxf(rmaxB, hBn);
    __syncthreads();
    h_lds[0][j] = hAn; h_lds[1][j] = hBn;
    __syncthreads();
  }
  doc_vec[(long)d0*512 + dir*256 + j]     = (lenA > 0) ? rmaxA : 0.0f;
  doc_vec[(long)(d0+1)*512 + dir*256 + j] = (lenB > 0) ? rmaxB : 0.0f;
}

// ---------------- doc-level GRU over 64 docs (B=1); grid 2 (dir); plain max ----------------
__global__ __launch_bounds__(256)
void k_doc(const float* __restrict__ xg,
           const float* __restrict__ W4h_f, const float* __restrict__ W4h_b,
           const float* __restrict__ bh_f, const float* __restrict__ bh_b,
           float* __restrict__ blog)
{
  __shared__ __align__(16) float h_lds[HID];
  const int dir = blockIdx.x;
  const int j = threadIdx.x;
  const float* W4h = dir ? W4h_b : W4h_f;
  const float* bh  = dir ? bh_b  : bh_f;
  const float bhr = bh[j], bhz = bh[j+256], bhn = bh[j+512];
  h_lds[j] = 0.0f;
  float rmax = -INFINITY;
  __syncthreads();
  for (int t = 0; t < NDOC; ++t) {
    const int row = dir ? (NDOC-1-t) : t;
    const float* xgr = xg + (long)row*1536 + dir*768;
    const float xr = xgr[j], xz = xgr[j+256], xn = xgr[j+512];
    float ar=bhr, az=bhz, an=bhn;
    for (int d4 = 0; d4 < HID/4; ++d4) {
      const float4 wr = *(const float4*)(W4h + ((long)d4*G3 + j      )*4);
      const float4 wz = *(const float4*)(W4h + ((long)d4*G3 + j + 256)*4);
      const float4 wn = *(const float4*)(W4h + ((long)d4*G3 + j + 512)*4);
      const float4 h4 = *(const float4*)(&h_lds[d4*4]);
      fma4(ar, wr, h4); fma4(az, wz, h4); fma4(an, wn, h4);
    }
    float rg = sigm(xr + ar), zg = sigm(xz + az);
    float ng = tanhfast(xn + rg*an);
    float hn = (1.0f - zg)*ng + zg*h_lds[j];
    rmax = fmaxf(rmax, hn);
    __syncthreads();
    h_lds[j] = hn;
    __syncthreads();
  }
  blog[dir*256 + j] = rmax;
}

// ---------------- scoring: content + salience + pos scores + bias ----------------
__global__ __launch_bounds__(256)
void k_score(const float* __restrict__ docs /*[2048,512]*/, const float* __restrict__ doc_vec,
             const float* __restrict__ blog, const float* __restrict__ W4sal,
             const float* __restrict__ w_content, const float* __restrict__ w_dpos,
             const float* __restrict__ w_spos, const float* __restrict__ doc_pos_tab,
             const float* __restrict__ sent_pos_tab, const float* __restrict__ sent_bias,
             const int* __restrict__ dlens, float* __restrict__ out)
{
  __shared__ __align__(16) float ctx[1024];
  __shared__ __align__(16) float cw[1024];   // [0:512) cproj, [512:1024) w_content
  const int n = blockIdx.x;
  const int j = threadIdx.x;
  ctx[j]       = blog[j];
  ctx[256 + j] = blog[256 + j];
  ctx[512 + j] = doc_vec[(long)n*512 + j];
  ctx[768 + j] = doc_vec[(long)n*512 + 256 + j];
  cw[512 + j]  = w_content[j];
  cw[768 + j]  = w_content[256 + j];
  __syncthreads();
  float acc0 = 0.0f, acc1 = 0.0f;
  for (int e4 = 0; e4 < 256; ++e4) {
    const float4 c4 = *(const float4*)(&ctx[e4*4]);
    const float4 w0 = *(const float4*)(W4sal + ((long)e4*512 + j      )*4);
    const float4 w1 = *(const float4*)(W4sal + ((long)e4*512 + j + 256)*4);
    fma4(acc0, w0, c4);
    fma4(acc1, w1, c4);
  }
  cw[j] = acc0; cw[j + 256] = acc1;
  __syncthreads();
  const int l = j >> 3, p = j & 7;
  const float* drow = docs + ((long)n*LSENT + l)*512;
  float pc = 0.0f, ps = 0.0f;
  for (int i = p*64; i < p*64 + 64; i += 4) {
    const float4 dv  = *(const float4*)(drow + i);
    const float4 wc4 = *(const float4*)(&cw[512 + i]);
    const float4 cp4 = *(const float4*)(&cw[i]);
    fma4(pc, dv, wc4);
    fma4(ps, dv, cp4);
  }
  #pragma unroll
  for (int o = 1; o < 8; o <<= 1) {
    pc += __shfl_xor(pc, o, 8);
    ps += __shfl_xor(ps, o, 8);
  }
  if (p == 0) {
    const int dlen = dlens[n];
    const int di = (n * PDOC) / NDOC;
    float ds = 0.0f;
    for (int i = 0; i < PDIMM; ++i) ds = fmaf(doc_pos_tab[(long)di*PDIMM + i], w_dpos[i], ds);
    const int safe = (dlen > 1) ? dlen : 1;
    int si = (l * PSENT) / safe;
    if (si > PSENT-1) si = PSENT-1;
    float ss = 0.0f;
    for (int i = 0; i < PDIMM; ++i) ss = fmaf(sent_pos_tab[(long)si*PDIMM + i], w_spos[i], ss);
    out[n*LSENT + l] = pc + ps + ds + ss + sent_bias[0];
  }
}

extern "C" void kernel_launch(void* const* d_in, const int* in_sizes, int n_in,
                              void* d_out, int out_size, void* d_ws, size_t ws_size,
                              hipStream_t stream)
{
  const int*   x        = (const int*)  d_in[0];
  const int*   doc_lens = (const int*)  d_in[1];
  const float* embed    = (const float*)d_in[2];
  const float* wWi_f = (const float*)d_in[3];
  const float* wWh_f = (const float*)d_in[4];
  const float* wbi_f = (const float*)d_in[5];
  const float* wbh_f = (const float*)d_in[6];
  const float* wWi_b = (const float*)d_in[7];
  const float* wWh_b = (const float*)d_in[8];
  const float* wbi_b = (const float*)d_in[9];
  const float* wbh_b = (const float*)d_in[10];
  const float* sWi_f = (const float*)d_in[11];
  const float* sWh_f = (const float*)d_in[12];
  const float* sbi_f = (const float*)d_in[13];
  const float* sbh_f = (const float*)d_in[14];
  const float* sWi_b = (const float*)d_in[15];
  const float* sWh_b = (const float*)d_in[16];
  const float* sbi_b = (const float*)d_in[17];
  const float* sbh_b = (const float*)d_in[18];
  const float* dWi_f = (const float*)d_in[19];
  const float* dWh_f = (const float*)d_in[20];
  const float* dbi_f = (const float*)d_in[21];
  const float* dbh_f = (const float*)d_in[22];
  const float* dWi_b = (const float*)d_in[23];
  const float* dWh_b = (const float*)d_in[24];
  const float* dbi_b = (const float*)d_in[25];
  const float* dbh_b = (const float*)d_in[26];
  const float* doc_pos_tab  = (const float*)d_in[27];
  const float* sent_pos_tab = (const float*)d_in[28];
  const float* w_content    = (const float*)d_in[29];
  const float* W_sal        = (const float*)d_in[30];
  const float* w_dpos       = (const float*)d_in[31];
  const float* w_spos       = (const float*)d_in[32];
  const float* sent_bias    = (const float*)d_in[33];

  float* ws = (float*)d_ws;

  TT tt;
  int idx = 0;
  auto add = [&](const float* src, long dst, int R, int Dk, int sh){
    tt.t[idx].src = src; tt.t[idx].dst = dst; tt.t[idx].cnt = (long)R*Dk;
    tt.t[idx].sh = sh; tt.t[idx].R = R; ++idx;
  };
  add(wWi_f, OFF_W4_wWi_f, 768, 128, 7);
  add(wWi_b, OFF_W4_wWi_b, 768, 128, 7);
  add(wWh_f, OFF_W4_wWh_f, 768, 256, 8);
  add(wWh_b, OFF_W4_wWh_b, 768, 256, 8);
  add(sWi_f, OFF_W4_sWi_f, 768, 512, 9);
  add(sWi_b, OFF_W4_sWi_b, 768, 512, 9);
  add(sWh_f, OFF_W4_sWh_f, 768, 256, 8);
  add(sWh_b, OFF_W4_sWh_b, 768, 256, 8);
  add(dWi_f, OFF_W4_dWi_f, 768, 512, 9);
  add(dWi_b, OFF_W4_dWi_b, 768, 512, 9);
  add(dWh_f, OFF_W4_dWh_f, 768, 256, 8);
  add(dWh_b, OFF_W4_dWh_b, 768, 256, 8);
  add(W_sal, OFF_W4_salT,  512, 1024, 10);
  long total = 0;
  for (int i = 0; i < 13; ++i) total += tt.t[i].cnt;   // 3,473,408

  k_transpose<<<(int)((total + 255)/256), 256, 0, stream>>>(tt, ws, total);
  k_lens<<<NSENT/256, 256, 0, stream>>>(x, (int*)(ws + OFF_LENS));

  k_word<<<256, 512, 0, stream>>>(x, embed,
      ws + OFF_W4_wWi_f, ws + OFF_W4_wWi_b, ws + OFF_W4_wWh_f, ws + OFF_W4_wWh_b,
      wbi_f, wbi_b, wbh_f, wbh_b,
      (const int*)(ws + OFF_LENS), ws + OFF_SENTVEC);

  k_gates<<<NSENT/8, 256, 0, stream>>>(ws + OFF_SENTVEC,
      ws + OFF_W4_sWi_f, ws + OFF_W4_sWi_b, sbi_f, sbi_b, ws + OFF_XGS);

  k_sent<<<NDOC, 256, 0, stream>>>(ws + OFF_XGS,
      ws + OFF_W4_sWh_f, ws + OFF_W4_sWh_b, sbh_f, sbh_b,
      doc_lens, ws + OFF_DOCVEC);

  k_gates<<<NDOC/8, 256, 0, stream>>>(ws + OFF_DOCVEC,
      ws + OFF_W4_dWi_f, ws + OFF_W4_dWi_b, dbi_f, dbi_b, ws + OFF_XGD);

  k_doc<<<2, 256, 0, stream>>>(ws + OFF_XGD,
      ws + OFF_W4_dWh_f, ws + OFF_W4_dWh_b, dbh_f, dbh_b, ws + OFF_BLOG);

  k_score<<<NDOC, 256, 0, stream>>>(ws + OFF_SENTVEC, ws + OFF_DOCVEC, ws + OFF_BLOG,
      ws + OFF_W4_salT, w_content, w_dpos, w_spos,
      doc_pos_tab, sent_pos_tab, sent_bias, doc_lens, (float*)d_out);
}

// Round 4
// 1880.112 us; speedup vs baseline: 1.5963x; 1.5963x over previous
//
#include <hip/hip_runtime.h>
#include <math.h>

#define HID 256
#define G3 768
#define DIM 128
#define TW 50
#define NSENT 2048
#define NDOC 64
#define LSENT 32
#define PDOC 50
#define PSENT 100
#define PDIMM 50

using i32x4 = __attribute__((ext_vector_type(4))) int;

// ---- i8 frag region (bytes at start of ws) ----
// W1f[294912] W2f[294912] W1b[294912] W2b[294912]  (48 mt x 6 kc x 64 lane x 16 e)
static constexpr long OFFB_W1F = 0;
static constexpr long OFFB_W2F = 294912;
static constexpr long OFFB_W1B = 589824;
static constexpr long OFFB_W2B = 884736;   // ends 1179648 B  (< 2359296 B = old float off 589824)

// ---- float offsets (unchanged from fp32 version; start beyond i8 region) ----
static constexpr long OFF_W4_sWi_f = 589824;
static constexpr long OFF_W4_sWi_b = 983040;
static constexpr long OFF_W4_sWh_f = 1376256;
static constexpr long OFF_W4_sWh_b = 1572864;
static constexpr long OFF_W4_dWi_f = 1769472;
static constexpr long OFF_W4_dWi_b = 2162688;
static constexpr long OFF_W4_dWh_f = 2555904;
static constexpr long OFF_W4_dWh_b = 2752512;
static constexpr long OFF_W4_salT  = 2949120;
static constexpr long OFF_LENS     = 3473408;
static constexpr long OFF_SENTVEC  = 3475456;   // [2048,512]
static constexpr long OFF_XGS      = 4524032;   // [2048,1536]
static constexpr long OFF_DOCVEC   = 7669760;   // [64,512]
static constexpr long OFF_XGD      = 7702528;   // [64,1536]
static constexpr long OFF_BLOG     = 7800832;   // [512]

#define SW_Q (0.3f/127.0f)
#define SX_Q (1.0f/127.0f)

__device__ __forceinline__ float sigm(float v){ return 1.0f/(1.0f+__expf(-v)); }
__device__ __forceinline__ float tanhfast(float v){ return 1.0f - 2.0f/(1.0f+__expf(2.0f*v)); }

__device__ __forceinline__ void fma4(float& acc, const float4 a, const float4 b){
  acc = fmaf(a.x, b.x, fmaf(a.y, b.y, fmaf(a.z, b.z, fmaf(a.w, b.w, acc))));
}

// quantize v (|v|<=1-ish) to i8 hi/lo at scale SX_Q
__device__ __forceinline__ void quant2(float v, int& a, int& b){
  float q1 = rintf(fminf(fmaxf(v*127.0f, -127.0f), 127.0f));
  a = (int)q1;
  float resid = v - q1*(1.0f/127.0f);
  b = (int)rintf(fminf(fmaxf(resid*32512.0f, -127.0f), 127.0f)); // 127*256
}
__device__ __forceinline__ int pack4(int a0,int a1,int a2,int a3){
  return (a0&255) | ((a1&255)<<8) | ((a2&255)<<16) | ((a3&255)<<24);
}

// ---------------- word-weight i8 frag prep ----------------
// frag elem (mt,kc,l,e) holds Wtilde[row=mt*16+(l&15)][k=kc*64+kmap(l>>4,e)],
// kmap(hi,e) = (e>>2)*16 + hi*4 + (e&3).  Wtilde = [Wh(256) | Wi(128)].
__global__ __launch_bounds__(256)
void k_prep_w(const float* __restrict__ wWh_f, const float* __restrict__ wWi_f,
              const float* __restrict__ wWh_b, const float* __restrict__ wWi_b,
              signed char* __restrict__ W1f, signed char* __restrict__ W2f,
              signed char* __restrict__ W1b, signed char* __restrict__ W2b)
{
  int g = blockIdx.x*256 + threadIdx.x;           // 0..589823
  int d = g / 294912;
  int r = g % 294912;
  int mt  = r / 6144;
  int rem = r % 6144;
  int kc  = rem >> 10;
  int l   = (rem >> 4) & 63;
  int e   = r & 15;
  int row = mt*16 + (l & 15);
  int hi  = l >> 4;
  int k   = kc*64 + ((e >> 2)*16 + hi*4 + (e & 3));
  const float* Wh = d ? wWh_b : wWh_f;
  const float* Wi = d ? wWi_b : wWi_f;
  float wv = (k < 256) ? Wh[(long)row*256 + k] : Wi[(long)row*128 + (k - 256)];
  float q1 = rintf(fminf(fmaxf(wv*(1.0f/SW_Q), -127.0f), 127.0f));
  float resid = wv - q1*SW_Q;
  float q2 = rintf(fminf(fmaxf(resid*(256.0f/SW_Q), -127.0f), 127.0f));
  signed char* W1 = d ? W1b : W1f;
  signed char* W2 = d ? W2b : W2f;
  W1[r] = (signed char)(int)q1;
  W2[r] = (signed char)(int)q2;
}

struct TD { const float* src; long dst; long cnt; int sh; int R; };
struct TT { TD t[9]; };

// packed-4 transpose: dst[((col>>2)*R + j)*4 + (col&3)] = src[j*Dk + col]
__global__ __launch_bounds__(256) void k_transpose(TT tt, float* __restrict__ ws, long total){
  long g = (long)blockIdx.x*256 + threadIdx.x;
  if (g >= total) return;
  int k = 0; long r = g;
  while (r >= tt.t[k].cnt) { r -= tt.t[k].cnt; ++k; }
  const float* src = tt.t[k].src;
  int sh = tt.t[k].sh; int R = tt.t[k].R;
  long j = r >> sh;
  int col = (int)(r & ((1L<<sh)-1));
  ws[tt.t[k].dst + (((long)(col>>2))*R + j)*4 + (col&3)] = src[r];
}

__global__ __launch_bounds__(256) void k_lens(const int* __restrict__ x, int* __restrict__ lens){
  int n = blockIdx.x*256 + threadIdx.x;
  if (n >= NSENT) return;
  int c = 0;
  for (int t = 0; t < TW; ++t) c += (x[n*TW + t] != 0) ? 1 : 0;
  lens[n] = c;
}

// ---------------- word-level BiGRU via i8 hi/lo MFMA ----------------
// 256 blocks = 128 sent-groups x 2 dirs; 512 thr = 8 waves.
// wave w owns m-tiles r:{2w,2w+1} z:{+16} n:{+32}; each thread: 8 j-values x 1 sentence.
__global__ __launch_bounds__(512, 2)
void k_word_i8(const int* __restrict__ x, const float* __restrict__ embed,
               const signed char* __restrict__ W1f, const signed char* __restrict__ W2f,
               const signed char* __restrict__ W1b, const signed char* __restrict__ W2b,
               const float* __restrict__ bi_f, const float* __restrict__ bi_b,
               const float* __restrict__ bh_f, const float* __restrict__ bh_b,
               const int* __restrict__ lens, float* __restrict__ sent_vec)
{
  __shared__ __align__(16) signed char X1[6*1024];
  __shared__ __align__(16) signed char X2[6*1024];
  const int blk = blockIdx.x;
  const int dir = blk & 1;
  const int n0  = (blk >> 1) * 16;
  const int tid = threadIdx.x;
  const int w    = tid >> 6;
  const int lane = tid & 63;
  const int hi4  = lane >> 4;
  const int s    = lane & 15;
  const signed char* W1 = dir ? W1b : W1f;
  const signed char* W2 = dir ? W2b : W2f;
  const float* bi = dir ? bi_b : bi_f;
  const float* bh = dir ? bh_b : bh_f;

  float b_r[2][4], b_z[2][4], b_nx[2][4], b_nh[2][4];
  #pragma unroll
  for (int q = 0; q < 2; ++q)
    #pragma unroll
    for (int i = 0; i < 4; ++i) {
      int j = (2*w + q)*16 + hi4*4 + i;
      b_r[q][i]  = bi[j]     + bh[j];
      b_z[q][i]  = bi[j+256] + bh[j+256];
      b_nx[q][i] = bi[j+512];
      b_nh[q][i] = bh[j+512];
    }
  float hold[2][4] = {{0.f,0.f,0.f,0.f},{0.f,0.f,0.f,0.f}};
  float rmax[2][4];
  #pragma unroll
  for (int q = 0; q < 2; ++q)
    #pragma unroll
    for (int i = 0; i < 4; ++i) rmax[q][i] = -INFINITY;
  const int len_s = lens[n0 + s];

  // zero h-region (kc 0..3 = first 4096 B of each buffer)
  for (int i2 = tid; i2 < 1024; i2 += 512) { ((int*)X1)[i2] = 0; ((int*)X2)[i2] = 0; }

  // gather e(t=0) into kc 4..5
  {
    const int tx = dir ? (TW-1) : 0;
    const int s2 = tid >> 5;
    const int d0 = (tid & 31) * 4;
    const int tok = x[(n0 + s2)*TW + tx];
    const float4 ev = *(const float4*)(embed + (long)tok*DIM + d0);
    int a0,a1,a2,a3,c0,c1v,c2v,c3;
    quant2(ev.x,a0,c0); quant2(ev.y,a1,c1v); quant2(ev.z,a2,c2v); quant2(ev.w,a3,c3);
    const int kc = 4 + (d0 >> 6);
    const int kk = d0 & 63;
    const int ee0 = (kk >> 4) << 2;
    const int lp  = ((kk >> 2) & 3)*16 + s2;
    const int off = kc*1024 + lp*16 + ee0;
    *(int*)(X1 + off) = pack4(a0,a1,a2,a3);
    *(int*)(X2 + off) = pack4(c0,c1v,c2v,c3);
  }
  __syncthreads();

  for (int t = 0; t < TW; ++t) {
    i32x4 p1r[2], p23r[2], p1z[2], p23z[2], p1nh[2], p23nh[2], p1nx[2], p23nx[2];
    #pragma unroll
    for (int q = 0; q < 2; ++q) {
      p1r[q] = i32x4{0,0,0,0};  p23r[q] = i32x4{0,0,0,0};
      p1z[q] = i32x4{0,0,0,0};  p23z[q] = i32x4{0,0,0,0};
      p1nh[q]= i32x4{0,0,0,0};  p23nh[q]= i32x4{0,0,0,0};
      p1nx[q]= i32x4{0,0,0,0};  p23nx[q]= i32x4{0,0,0,0};
    }
    // ---- h-part: kc 0..3 ----
    #pragma unroll
    for (int kc = 0; kc < 4; ++kc) {
      const i32x4 x1v = *(const i32x4*)(X1 + kc*1024 + lane*16);
      const i32x4 x2v = *(const i32x4*)(X2 + kc*1024 + lane*16);
      #pragma unroll
      for (int q = 0; q < 2; ++q) {
        const int mtr = 2*w + q;
        {
          const long fo = ((long)(mtr*6 + kc))*1024 + lane*16;
          const i32x4 a1 = *(const i32x4*)(W1 + fo);
          const i32x4 a2 = *(const i32x4*)(W2 + fo);
          p1r[q]  = __builtin_amdgcn_mfma_i32_16x16x64_i8(a1, x1v, p1r[q], 0,0,0);
          p23r[q] = __builtin_amdgcn_mfma_i32_16x16x64_i8(a1, x2v, p23r[q],0,0,0);
          p23r[q] = __builtin_amdgcn_mfma_i32_16x16x64_i8(a2, x1v, p23r[q],0,0,0);
        }
        {
          const long fo = ((long)((mtr+16)*6 + kc))*1024 + lane*16;
          const i32x4 a1 = *(const i32x4*)(W1 + fo);
          const i32x4 a2 = *(const i32x4*)(W2 + fo);
          p1z[q]  = __builtin_amdgcn_mfma_i32_16x16x64_i8(a1, x1v, p1z[q], 0,0,0);
          p23z[q] = __builtin_amdgcn_mfma_i32_16x16x64_i8(a1, x2v, p23z[q],0,0,0);
          p23z[q] = __builtin_amdgcn_mfma_i32_16x16x64_i8(a2, x1v, p23z[q],0,0,0);
        }
        {
          const long fo = ((long)((mtr+32)*6 + kc))*1024 + lane*16;
          const i32x4 a1 = *(const i32x4*)(W1 + fo);
          const i32x4 a2 = *(const i32x4*)(W2 + fo);
          p1nh[q]  = __builtin_amdgcn_mfma_i32_16x16x64_i8(a1, x1v, p1nh[q], 0,0,0);
          p23nh[q] = __builtin_amdgcn_mfma_i32_16x16x64_i8(a1, x2v, p23nh[q],0,0,0);
          p23nh[q] = __builtin_amdgcn_mfma_i32_16x16x64_i8(a2, x1v, p23nh[q],0,0,0);
        }
      }
    }
    // ---- e-part: kc 4..5 (n-gate goes to separate x-accumulator) ----
    #pragma unroll
    for (int kc = 4; kc < 6; ++kc) {
      const i32x4 x1v = *(const i32x4*)(X1 + kc*1024 + lane*16);
      const i32x4 x2v = *(const i32x4*)(X2 + kc*1024 + lane*16);
      #pragma unroll
      for (int q = 0; q < 2; ++q) {
        const int mtr = 2*w + q;
        {
          const long fo = ((long)(mtr*6 + kc))*1024 + lane*16;
          const i32x4 a1 = *(const i32x4*)(W1 + fo);
          const i32x4 a2 = *(const i32x4*)(W2 + fo);
          p1r[q]  = __builtin_amdgcn_mfma_i32_16x16x64_i8(a1, x1v, p1r[q], 0,0,0);
          p23r[q] = __builtin_amdgcn_mfma_i32_16x16x64_i8(a1, x2v, p23r[q],0,0,0);
          p23r[q] = __builtin_amdgcn_mfma_i32_16x16x64_i8(a2, x1v, p23r[q],0,0,0);
        }
        {
          const long fo = ((long)((mtr+16)*6 + kc))*1024 + lane*16;
          const i32x4 a1 = *(const i32x4*)(W1 + fo);
          const i32x4 a2 = *(const i32x4*)(W2 + fo);
          p1z[q]  = __builtin_amdgcn_mfma_i32_16x16x64_i8(a1, x1v, p1z[q], 0,0,0);
          p23z[q] = __builtin_amdgcn_mfma_i32_16x16x64_i8(a1, x2v, p23z[q],0,0,0);
          p23z[q] = __builtin_amdgcn_mfma_i32_16x16x64_i8(a2, x1v, p23z[q],0,0,0);
        }
        {
          const long fo = ((long)((mtr+32)*6 + kc))*1024 + lane*16;
          const i32x4 a1 = *(const i32x4*)(W1 + fo);
          const i32x4 a2 = *(const i32x4*)(W2 + fo);
          p1nx[q]  = __builtin_amdgcn_mfma_i32_16x16x64_i8(a1, x1v, p1nx[q], 0,0,0);
          p23nx[q] = __builtin_amdgcn_mfma_i32_16x16x64_i8(a1, x2v, p23nx[q],0,0,0);
          p23nx[q] = __builtin_amdgcn_mfma_i32_16x16x64_i8(a2, x1v, p23nx[q],0,0,0);
        }
      }
    }
    // ---- GRU nonlinearity (i32 accs are exact; convert once) ----
    const float cc1 = SW_Q * SX_Q;
    const float cc2 = cc1 * (1.0f/256.0f);
    #pragma unroll
    for (int q = 0; q < 2; ++q)
      #pragma unroll
      for (int i = 0; i < 4; ++i) {
        float ar = fmaf(cc1, (float)p1r[q][i],  fmaf(cc2, (float)p23r[q][i],  b_r[q][i]));
        float az = fmaf(cc1, (float)p1z[q][i],  fmaf(cc2, (float)p23z[q][i],  b_z[q][i]));
        float ah = fmaf(cc1, (float)p1nh[q][i], fmaf(cc2, (float)p23nh[q][i], b_nh[q][i]));
        float ax = fmaf(cc1, (float)p1nx[q][i], fmaf(cc2, (float)p23nx[q][i], b_nx[q][i]));
        float rg = sigm(ar);
        float zg = sigm(az);
        float ng = tanhfast(ax + rg*ah);
        float hv = (1.0f - zg)*ng + zg*hold[q][i];
        hold[q][i] = hv;
        bool inm = dir ? (t >= TW - len_s) : (t < len_s);
        if (inm) rmax[q][i] = fmaxf(rmax[q][i], hv);
      }
    __syncthreads();   // all waves done reading X before overwrite
    // ---- write h(t) into kc 0..3 ----
    #pragma unroll
    for (int q = 0; q < 2; ++q) {
      const int j0 = (2*w + q)*16 + hi4*4;
      const int kcw = j0 >> 6;
      const int kk  = j0 & 63;
      const int ee0 = (kk >> 4) << 2;
      const int lp  = ((kk >> 2) & 3)*16 + s;
      const int off = kcw*1024 + lp*16 + ee0;
      int a0,a1,a2,a3,c0,c1v,c2v,c3;
      quant2(hold[q][0],a0,c0); quant2(hold[q][1],a1,c1v);
      quant2(hold[q][2],a2,c2v); quant2(hold[q][3],a3,c3);
      *(int*)(X1 + off) = pack4(a0,a1,a2,a3);
      *(int*)(X2 + off) = pack4(c0,c1v,c2v,c3);
    }
    // ---- gather e(t+1) into kc 4..5 ----
    if (t < TW-1) {
      const int tx = dir ? (TW-2-t) : (t+1);
      const int s2 = tid >> 5;
      const int d0 = (tid & 31) * 4;
      const int tok = x[(n0 + s2)*TW + tx];
      const float4 ev = *(const float4*)(embed + (long)tok*DIM + d0);
      int a0,a1,a2,a3,c0,c1v,c2v,c3;
      quant2(ev.x,a0,c0); quant2(ev.y,a1,c1v); quant2(ev.z,a2,c2v); quant2(ev.w,a3,c3);
      const int kc = 4 + (d0 >> 6);
      const int kk = d0 & 63;
      const int ee0 = (kk >> 4) << 2;
      const int lp  = ((kk >> 2) & 3)*16 + s2;
      const int off = kc*1024 + lp*16 + ee0;
      *(int*)(X1 + off) = pack4(a0,a1,a2,a3);
      *(int*)(X2 + off) = pack4(c0,c1v,c2v,c3);
    }
    __syncthreads();
  }
  // ---- store masked max ----
  #pragma unroll
  for (int q = 0; q < 2; ++q)
    #pragma unroll
    for (int i = 0; i < 4; ++i) {
      int j = (2*w + q)*16 + hi4*4 + i;
      float v = (len_s > 0) ? rmax[q][i] : 0.0f;
      sent_vec[(long)(n0+s)*(2*HID) + dir*HID + j] = v;
    }
}

// ---------------- input-gate GEMM: out[b, 0:768]=fwd gates, [768:1536]=bwd; Din=512 ----------------
__global__ __launch_bounds__(256)
void k_gates(const float* __restrict__ A,
             const float* __restrict__ W4f, const float* __restrict__ W4b,
             const float* __restrict__ bif, const float* __restrict__ bib,
             float* __restrict__ out)
{
  __shared__ __align__(16) float a_lds[8][512];
  const int r0 = blockIdx.x * 8;
  const int j  = threadIdx.x;
  #pragma unroll
  for (int q = 0; q < 4; ++q) {
    int fi = j + q*256;
    int rr = fi >> 7; int cc = (fi & 127) * 4;
    *(float4*)(&a_lds[rr][cc]) = *(const float4*)(A + (long)(r0+rr)*512 + cc);
  }
  __syncthreads();
  float acc[6][8];
  {
    float bias[6] = { bif[j], bif[j+256], bif[j+512], bib[j], bib[j+256], bib[j+512] };
    #pragma unroll
    for (int k = 0; k < 6; ++k)
      #pragma unroll
      for (int rr = 0; rr < 8; ++rr) acc[k][rr] = bias[k];
  }
  for (int d4 = 0; d4 < 128; ++d4) {
    float4 w0 = *(const float4*)(W4f + ((long)d4*G3 + j      )*4);
    float4 w1 = *(const float4*)(W4f + ((long)d4*G3 + j + 256)*4);
    float4 w2 = *(const float4*)(W4f + ((long)d4*G3 + j + 512)*4);
    float4 w3 = *(const float4*)(W4b + ((long)d4*G3 + j      )*4);
    float4 w4v= *(const float4*)(W4b + ((long)d4*G3 + j + 256)*4);
    float4 w5 = *(const float4*)(W4b + ((long)d4*G3 + j + 512)*4);
    #pragma unroll
    for (int rr = 0; rr < 8; ++rr){
      const float4 a4 = *(const float4*)(&a_lds[rr][d4*4]);
      fma4(acc[0][rr], w0, a4);
      fma4(acc[1][rr], w1, a4);
      fma4(acc[2][rr], w2, a4);
      fma4(acc[3][rr], w3, a4);
      fma4(acc[4][rr], w4v, a4);
      fma4(acc[5][rr], w5, a4);
    }
  }
  #pragma unroll
  for (int rr = 0; rr < 8; ++rr){
    long base = (long)(r0+rr)*1536;
    out[base + j      ] = acc[0][rr];
    out[base + j + 256] = acc[1][rr];
    out[base + j + 512] = acc[2][rr];
    out[base + j + 768] = acc[3][rr];
    out[base + j +1024] = acc[4][rr];
    out[base + j +1280] = acc[5][rr];
  }
}

// ---------------- sentence-level BiGRU recurrence (xg precomputed); 2 docs per block ----------------
__global__ __launch_bounds__(256)
void k_sent(const float* __restrict__ xg,
            const float* __restrict__ W4h_f, const float* __restrict__ W4h_b,
            const float* __restrict__ bh_f, const float* __restrict__ bh_b,
            const int* __restrict__ dlens, float* __restrict__ doc_vec)
{
  __shared__ __align__(16) float h_lds[2][HID];
  const int blk = blockIdx.x;
  const int dir = blk & 1;
  const int d0  = (blk >> 1) * 2;
  const int j   = threadIdx.x;
  const float* W4h = dir ? W4h_b : W4h_f;
  const float* bh  = dir ? bh_b  : bh_f;
  const float bhr = bh[j], bhz = bh[j+256], bhn = bh[j+512];
  const int lenA = dlens[d0], lenB = dlens[d0+1];
  h_lds[0][j] = 0.0f; h_lds[1][j] = 0.0f;
  float rmaxA = -INFINITY, rmaxB = -INFINITY;
  __syncthreads();
  for (int t = 0; t < LSENT; ++t) {
    const int row = dir ? (LSENT-1-t) : t;
    const float* xga = xg + ((long)(d0*LSENT + row))*1536 + dir*768;
    const float* xgb = xg + ((long)((d0+1)*LSENT + row))*1536 + dir*768;
    const float xrA = xga[j], xzA = xga[j+256], xnA = xga[j+512];
    const float xrB = xgb[j], xzB = xgb[j+256], xnB = xgb[j+512];
    float arA=bhr, azA=bhz, anA=bhn, arB=bhr, azB=bhz, anB=bhn;
    for (int d4 = 0; d4 < HID/4; ++d4) {
      const float4 wr = *(const float4*)(W4h + ((long)d4*G3 + j      )*4);
      const float4 wz = *(const float4*)(W4h + ((long)d4*G3 + j + 256)*4);
      const float4 wn = *(const float4*)(W4h + ((long)d4*G3 + j + 512)*4);
      const float4 hA = *(const float4*)(&h_lds[0][d4*4]);
      const float4 hB = *(const float4*)(&h_lds[1][d4*4]);
      fma4(arA, wr, hA); fma4(azA, wz, hA); fma4(anA, wn, hA);
      fma4(arB, wr, hB); fma4(azB, wz, hB); fma4(anB, wn, hB);
    }
    float rA = sigm(xrA + arA), zA = sigm(xzA + azA);
    float nA = tanhfast(xnA + rA*anA);
    float hAn = (1.0f - zA)*nA + zA*h_lds[0][j];
    float rB = sigm(xrB + arB), zB = sigm(xzB + azB);
    float nB = tanhfast(xnB + rB*anB);
    float hBn = (1.0f - zB)*nB + zB*h_lds[1][j];
    bool mA = dir ? (t >= LSENT - lenA) : (t < lenA);
    bool mB = dir ? (t >= LSENT - lenB) : (t < lenB);
    if (mA) rmaxA = fmaxf(rmaxA, hAn);
    if (mB) rmaxB = fmaxf(rmaxB, hBn);
    __syncthreads();
    h_lds[0][j] = hAn; h_lds[1][j] = hBn;
    __syncthreads();
  }
  doc_vec[(long)d0*512 + dir*256 + j]     = (lenA > 0) ? rmaxA : 0.0f;
  doc_vec[(long)(d0+1)*512 + dir*256 + j] = (lenB > 0) ? rmaxB : 0.0f;
}

// ---------------- doc-level GRU over 64 docs (B=1); grid 2 (dir); plain max ----------------
__global__ __launch_bounds__(256)
void k_doc(const float* __restrict__ xg,
           const float* __restrict__ W4h_f, const float* __restrict__ W4h_b,
           const float* __restrict__ bh_f, const float* __restrict__ bh_b,
           float* __restrict__ blog)
{
  __shared__ __align__(16) float h_lds[HID];
  const int dir = blockIdx.x;
  const int j = threadIdx.x;
  const float* W4h = dir ? W4h_b : W4h_f;
  const float* bh  = dir ? bh_b  : bh_f;
  const float bhr = bh[j], bhz = bh[j+256], bhn = bh[j+512];
  h_lds[j] = 0.0f;
  float rmax = -INFINITY;
  __syncthreads();
  for (int t = 0; t < NDOC; ++t) {
    const int row = dir ? (NDOC-1-t) : t;
    const float* xgr = xg + (long)row*1536 + dir*768;
    const float xr = xgr[j], xz = xgr[j+256], xn = xgr[j+512];
    float ar=bhr, az=bhz, an=bhn;
    for (int d4 = 0; d4 < HID/4; ++d4) {
      const float4 wr = *(const float4*)(W4h + ((long)d4*G3 + j      )*4);
      const float4 wz = *(const float4*)(W4h + ((long)d4*G3 + j + 256)*4);
      const float4 wn = *(const float4*)(W4h + ((long)d4*G3 + j + 512)*4);
      const float4 h4 = *(const float4*)(&h_lds[d4*4]);
      fma4(ar, wr, h4); fma4(az, wz, h4); fma4(an, wn, h4);
    }
    float rg = sigm(xr + ar), zg = sigm(xz + az);
    float ng = tanhfast(xn + rg*an);
    float hn = (1.0f - zg)*ng + zg*h_lds[j];
    rmax = fmaxf(rmax, hn);
    __syncthreads();
    h_lds[j] = hn;
    __syncthreads();
  }
  blog[dir*256 + j] = rmax;
}

// ---------------- scoring: content + salience + pos scores + bias ----------------
__global__ __launch_bounds__(256)
void k_score(const float* __restrict__ docs /*[2048,512]*/, const float* __restrict__ doc_vec,
             const float* __restrict__ blog, const float* __restrict__ W4sal,
             const float* __restrict__ w_content, const float* __restrict__ w_dpos,
             const float* __restrict__ w_spos, const float* __restrict__ doc_pos_tab,
             const float* __restrict__ sent_pos_tab, const float* __restrict__ sent_bias,
             const int* __restrict__ dlens, float* __restrict__ out)
{
  __shared__ __align__(16) float ctx[1024];
  __shared__ __align__(16) float cw[1024];   // [0:512) cproj, [512:1024) w_content
  const int n = blockIdx.x;
  const int j = threadIdx.x;
  ctx[j]       = blog[j];
  ctx[256 + j] = blog[256 + j];
  ctx[512 + j] = doc_vec[(long)n*512 + j];
  ctx[768 + j] = doc_vec[(long)n*512 + 256 + j];
  cw[512 + j]  = w_content[j];
  cw[768 + j]  = w_content[256 + j];
  __syncthreads();
  float acc0 = 0.0f, acc1 = 0.0f;
  for (int e4 = 0; e4 < 256; ++e4) {
    const float4 c4 = *(const float4*)(&ctx[e4*4]);
    const float4 w0 = *(const float4*)(W4sal + ((long)e4*512 + j      )*4);
    const float4 w1 = *(const float4*)(W4sal + ((long)e4*512 + j + 256)*4);
    fma4(acc0, w0, c4);
    fma4(acc1, w1, c4);
  }
  cw[j] = acc0; cw[j + 256] = acc1;
  __syncthreads();
  const int l = j >> 3, p = j & 7;
  const float* drow = docs + ((long)n*LSENT + l)*512;
  float pc = 0.0f, ps = 0.0f;
  for (int i = p*64; i < p*64 + 64; i += 4) {
    const float4 dv  = *(const float4*)(drow + i);
    const float4 wc4 = *(const float4*)(&cw[512 + i]);
    const float4 cp4 = *(const float4*)(&cw[i]);
    fma4(pc, dv, wc4);
    fma4(ps, dv, cp4);
  }
  #pragma unroll
  for (int o = 1; o < 8; o <<= 1) {
    pc += __shfl_xor(pc, o, 8);
    ps += __shfl_xor(ps, o, 8);
  }
  if (p == 0) {
    const int dlen = dlens[n];
    const int di = (n * PDOC) / NDOC;
    float ds = 0.0f;
    for (int i = 0; i < PDIMM; ++i) ds = fmaf(doc_pos_tab[(long)di*PDIMM + i], w_dpos[i], ds);
    const int safe = (dlen > 1) ? dlen : 1;
    int si = (l * PSENT) / safe;
    if (si > PSENT-1) si = PSENT-1;
    float ss = 0.0f;
    for (int i = 0; i < PDIMM; ++i) ss = fmaf(sent_pos_tab[(long)si*PDIMM + i], w_spos[i], ss);
    out[n*LSENT + l] = pc + ps + ds + ss + sent_bias[0];
  }
}

extern "C" void kernel_launch(void* const* d_in, const int* in_sizes, int n_in,
                              void* d_out, int out_size, void* d_ws, size_t ws_size,
                              hipStream_t stream)
{
  const int*   x        = (const int*)  d_in[0];
  const int*   doc_lens = (const int*)  d_in[1];
  const float* embed    = (const float*)d_in[2];
  const float* wWi_f = (const float*)d_in[3];
  const float* wWh_f = (const float*)d_in[4];
  const float* wbi_f = (const float*)d_in[5];
  const float* wbh_f = (const float*)d_in[6];
  const float* wWi_b = (const float*)d_in[7];
  const float* wWh_b = (const float*)d_in[8];
  const float* wbi_b = (const float*)d_in[9];
  const float* wbh_b = (const float*)d_in[10];
  const float* sWi_f = (const float*)d_in[11];
  const float* sWh_f = (const float*)d_in[12];
  const float* sbi_f = (const float*)d_in[13];
  const float* sbh_f = (const float*)d_in[14];
  const float* sWi_b = (const float*)d_in[15];
  const float* sWh_b = (const float*)d_in[16];
  const float* sbi_b = (const float*)d_in[17];
  const float* sbh_b = (const float*)d_in[18];
  const float* dWi_f = (const float*)d_in[19];
  const float* dWh_f = (const float*)d_in[20];
  const float* dbi_f = (const float*)d_in[21];
  const float* dbh_f = (const float*)d_in[22];
  const float* dWi_b = (const float*)d_in[23];
  const float* dWh_b = (const float*)d_in[24];
  const float* dbi_b = (const float*)d_in[25];
  const float* dbh_b = (const float*)d_in[26];
  const float* doc_pos_tab  = (const float*)d_in[27];
  const float* sent_pos_tab = (const float*)d_in[28];
  const float* w_content    = (const float*)d_in[29];
  const float* W_sal        = (const float*)d_in[30];
  const float* w_dpos       = (const float*)d_in[31];
  const float* w_spos       = (const float*)d_in[32];
  const float* sent_bias    = (const float*)d_in[33];

  float* ws = (float*)d_ws;
  signed char* wsb = (signed char*)d_ws;
  signed char* W1f = wsb + OFFB_W1F;
  signed char* W2f = wsb + OFFB_W2F;
  signed char* W1b = wsb + OFFB_W1B;
  signed char* W2b = wsb + OFFB_W2B;

  // word-weight i8 frags
  k_prep_w<<<2304, 256, 0, stream>>>(wWh_f, wWi_f, wWh_b, wWi_b, W1f, W2f, W1b, W2b);

  // fp32 packed-4 transposes for sentence/doc/salience weights
  TT tt;
  int idx = 0;
  auto add = [&](const float* src, long dst, int R, int Dk, int sh){
    tt.t[idx].src = src; tt.t[idx].dst = dst; tt.t[idx].cnt = (long)R*Dk;
    tt.t[idx].sh = sh; tt.t[idx].R = R; ++idx;
  };
  add(sWi_f, OFF_W4_sWi_f, 768, 512, 9);
  add(sWi_b, OFF_W4_sWi_b, 768, 512, 9);
  add(sWh_f, OFF_W4_sWh_f, 768, 256, 8);
  add(sWh_b, OFF_W4_sWh_b, 768, 256, 8);
  add(dWi_f, OFF_W4_dWi_f, 768, 512, 9);
  add(dWi_b, OFF_W4_dWi_b, 768, 512, 9);
  add(dWh_f, OFF_W4_dWh_f, 768, 256, 8);
  add(dWh_b, OFF_W4_dWh_b, 768, 256, 8);
  add(W_sal, OFF_W4_salT,  512, 1024, 10);
  long total = 0;
  for (int i = 0; i < 9; ++i) total += tt.t[i].cnt;   // 2,883,584

  k_transpose<<<(int)((total + 255)/256), 256, 0, stream>>>(tt, ws, total);
  k_lens<<<NSENT/256, 256, 0, stream>>>(x, (int*)(ws + OFF_LENS));

  k_word_i8<<<256, 512, 0, stream>>>(x, embed, W1f, W2f, W1b, W2b,
      wbi_f, wbi_b, wbh_f, wbh_b,
      (const int*)(ws + OFF_LENS), ws + OFF_SENTVEC);

  k_gates<<<NSENT/8, 256, 0, stream>>>(ws + OFF_SENTVEC,
      ws + OFF_W4_sWi_f, ws + OFF_W4_sWi_b, sbi_f, sbi_b, ws + OFF_XGS);

  k_sent<<<NDOC, 256, 0, stream>>>(ws + OFF_XGS,
      ws + OFF_W4_sWh_f, ws + OFF_W4_sWh_b, sbh_f, sbh_b,
      doc_lens, ws + OFF_DOCVEC);

  k_gates<<<NDOC/8, 256, 0, stream>>>(ws + OFF_DOCVEC,
      ws + OFF_W4_dWi_f, ws + OFF_W4_dWi_b, dbi_f, dbi_b, ws + OFF_XGD);

  k_doc<<<2, 256, 0, stream>>>(ws + OFF_XGD,
      ws + OFF_W4_dWh_f, ws + OFF_W4_dWh_b, dbh_f, dbh_b, ws + OFF_BLOG);

  k_score<<<NDOC, 256, 0, stream>>>(ws + OFF_SENTVEC, ws + OFF_DOCVEC, ws + OFF_BLOG,
      ws + OFF_W4_salT, w_content, w_dpos, w_spos,
      doc_pos_tab, sent_pos_tab, sent_bias, doc_lens, (float*)d_out);
}

// Round 5
// 1752.737 us; speedup vs baseline: 1.7123x; 1.0727x over previous
//
#include <hip/hip_runtime.h>
#include <math.h>

#define HID 256
#define G3 768
#define DIM 128
#define TW 50
#define NSENT 2048
#define NDOC 64
#define LSENT 32
#define PDOC 50
#define PSENT 100
#define PDIMM 50

using i32x4 = __attribute__((ext_vector_type(4))) int;

// ---- i8 frag regions (bytes at start of ws) ----
static constexpr long OFFB_W1F  = 0;         // word: 48mt x 6kc x 1024B
static constexpr long OFFB_W2F  = 294912;
static constexpr long OFFB_W1B  = 589824;
static constexpr long OFFB_W2B  = 884736;
static constexpr long OFFB_SW1F = 1179648;   // sent Wh: 48mt x 4kc x 1024B
static constexpr long OFFB_SW2F = 1376256;
static constexpr long OFFB_SW1B = 1572864;
static constexpr long OFFB_SW2B = 1769472;
static constexpr long OFFB_DW1F = 1966080;   // doc Wh
static constexpr long OFFB_DW2F = 2162688;
static constexpr long OFFB_DW1B = 2359296;
static constexpr long OFFB_DW2B = 2555904;   // ends 2752512 B

// ---- float offsets (after i8 region: 2752512/4 = 688128) ----
static constexpr long OFF_W4_sWi_f = 688128;
static constexpr long OFF_W4_sWi_b = 1081344;
static constexpr long OFF_W4_dWi_f = 1474560;
static constexpr long OFF_W4_dWi_b = 1867776;
static constexpr long OFF_W4_salT  = 2260992;
static constexpr long OFF_LENS     = 2785280;
static constexpr long OFF_SENTVEC  = 2787328;   // [2048,512]
static constexpr long OFF_XGS      = 3835904;   // [2048,1536]
static constexpr long OFF_DOCVEC   = 6981632;   // [64,512]
static constexpr long OFF_XGD      = 7014400;   // [64,1536]
static constexpr long OFF_BLOG     = 7112704;   // [512]  (ends 28.45 MB)

#define SW_Q (0.3f/127.0f)
#define SX_Q (1.0f/127.0f)

__device__ __forceinline__ float sigm(float v){ return 1.0f/(1.0f+__expf(-v)); }
__device__ __forceinline__ float tanhfast(float v){ return 1.0f - 2.0f/(1.0f+__expf(2.0f*v)); }

__device__ __forceinline__ void fma4(float& acc, const float4 a, const float4 b){
  acc = fmaf(a.x, b.x, fmaf(a.y, b.y, fmaf(a.z, b.z, fmaf(a.w, b.w, acc))));
}

__device__ __forceinline__ void quant2(float v, int& a, int& b){
  float q1 = rintf(fminf(fmaxf(v*127.0f, -127.0f), 127.0f));
  a = (int)q1;
  float resid = v - q1*(1.0f/127.0f);
  b = (int)rintf(fminf(fmaxf(resid*32512.0f, -127.0f), 127.0f)); // 127*256
}
__device__ __forceinline__ int pack4(int a0,int a1,int a2,int a3){
  return (a0&255) | ((a1&255)<<8) | ((a2&255)<<16) | ((a3&255)<<24);
}

// hi/lo 3-pass MFMA helper: p1 += a1*x1 ; p23 += a1*x2 + a2*x1
__device__ __forceinline__ void mfma3(const signed char* __restrict__ W1,
                                      const signed char* __restrict__ W2, long fo,
                                      i32x4 x1v, i32x4 x2v, i32x4& p1, i32x4& p23){
  const i32x4 a1 = *(const i32x4*)(W1 + fo);
  const i32x4 a2 = *(const i32x4*)(W2 + fo);
  p1  = __builtin_amdgcn_mfma_i32_16x16x64_i8(a1, x1v, p1, 0,0,0);
  p23 = __builtin_amdgcn_mfma_i32_16x16x64_i8(a1, x2v, p23,0,0,0);
  p23 = __builtin_amdgcn_mfma_i32_16x16x64_i8(a2, x1v, p23,0,0,0);
}

// ---------------- generic i8 weight frag prep ----------------
// frag elem (mt,kc,l,e): W[row=mt*16+(l&15)][k=kc*64+(e>>2)*16+(l>>4)*4+(e&3)]
// k<256 -> Wh[row][k], else Wi[row][k-256]
struct PE { const float* Wh; const float* Wi; signed char* d1; signed char* d2; long cnt; int nkc; };
struct PP { PE e[6]; };
__global__ __launch_bounds__(256) void k_prep(PP pp, long total){
  long g = (long)blockIdx.x*256 + threadIdx.x;
  if (g >= total) return;
  int k = 0; long r = g;
  while (r >= pp.e[k].cnt) { r -= pp.e[k].cnt; ++k; }
  const float* Wh = pp.e[k].Wh;
  const float* Wi = pp.e[k].Wi;
  int span = pp.e[k].nkc << 10;
  int mt  = (int)(r / span);
  int rem = (int)(r % span);
  int kc  = rem >> 10;
  int l   = (rem >> 4) & 63;
  int e16 = rem & 15;
  int row = mt*16 + (l & 15);
  int kk  = kc*64 + ((e16>>2)*16 + (l>>4)*4 + (e16&3));
  float wv = (kk < 256) ? Wh[(long)row*256 + kk] : Wi[(long)row*128 + (kk-256)];
  float q1 = rintf(fminf(fmaxf(wv*(1.0f/SW_Q), -127.0f), 127.0f));
  float resid = wv - q1*SW_Q;
  float q2 = rintf(fminf(fmaxf(resid*(256.0f/SW_Q), -127.0f), 127.0f));
  pp.e[k].d1[r] = (signed char)(int)q1;
  pp.e[k].d2[r] = (signed char)(int)q2;
}

struct TD { const float* src; long dst; long cnt; int sh; int R; };
struct TT { TD t[5]; };

// packed-4 transpose: dst[((col>>2)*R + j)*4 + (col&3)] = src[j*Dk + col]
__global__ __launch_bounds__(256) void k_transpose(TT tt, float* __restrict__ ws, long total){
  long g = (long)blockIdx.x*256 + threadIdx.x;
  if (g >= total) return;
  int k = 0; long r = g;
  while (r >= tt.t[k].cnt) { r -= tt.t[k].cnt; ++k; }
  const float* src = tt.t[k].src;
  int sh = tt.t[k].sh; int R = tt.t[k].R;
  long j = r >> sh;
  int col = (int)(r & ((1L<<sh)-1));
  ws[tt.t[k].dst + (((long)(col>>2))*R + j)*4 + (col&3)] = src[r];
}

__global__ __launch_bounds__(256) void k_lens(const int* __restrict__ x, int* __restrict__ lens){
  int n = blockIdx.x*256 + threadIdx.x;
  if (n >= NSENT) return;
  int c = 0;
  for (int t = 0; t < TW; ++t) c += (x[n*TW + t] != 0) ? 1 : 0;
  lens[n] = c;
}

// ---------------- word-level BiGRU via i8 hi/lo MFMA, 16 waves ----------------
// 256 blocks = 128 sent-groups x 2 dirs; 1024 thr = 16 waves; wave w owns m-triple {w, w+16, w+32}.
__global__ __launch_bounds__(1024, 4)
void k_word_i8(const int* __restrict__ x, const float* __restrict__ embed,
               const signed char* __restrict__ W1f, const signed char* __restrict__ W2f,
               const signed char* __restrict__ W1b, const signed char* __restrict__ W2b,
               const float* __restrict__ bi_f, const float* __restrict__ bi_b,
               const float* __restrict__ bh_f, const float* __restrict__ bh_b,
               const int* __restrict__ lens, float* __restrict__ sent_vec)
{
  __shared__ __align__(16) signed char X1[6*1024];
  __shared__ __align__(16) signed char X2[6*1024];
  const int blk = blockIdx.x;
  const int dir = blk & 1;
  const int n0  = (blk >> 1) * 16;
  const int tid = threadIdx.x;
  const int w    = tid >> 6;      // 0..15
  const int lane = tid & 63;
  const int hi4  = lane >> 4;
  const int s    = lane & 15;
  const int j0   = w*16 + hi4*4;
  const signed char* W1 = dir ? W1b : W1f;
  const signed char* W2 = dir ? W2b : W2f;
  const float* bi = dir ? bi_b : bi_f;
  const float* bh = dir ? bh_b : bh_f;

  float b_r[4], b_z[4], b_nx[4], b_nh[4];
  #pragma unroll
  for (int i = 0; i < 4; ++i) {
    int j = j0 + i;
    b_r[i]  = bi[j]     + bh[j];
    b_z[i]  = bi[j+256] + bh[j+256];
    b_nx[i] = bi[j+512];
    b_nh[i] = bh[j+512];
  }
  float hold[4] = {0.f,0.f,0.f,0.f};
  float rmax[4] = {-INFINITY,-INFINITY,-INFINITY,-INFINITY};
  const int len_s = lens[n0 + s];

  for (int i2 = tid; i2 < 1536; i2 += 1024) { ((int*)X1)[i2] = 0; ((int*)X2)[i2] = 0; }

  // gather e(t=0) into kc 4..5 (embed row 0 is zeros per setup)
  if (tid < 512) {
    const int tx = dir ? (TW-1) : 0;
    const int s2 = tid >> 5;
    const int d0 = (tid & 31) * 4;
    const int tok = x[(n0 + s2)*TW + tx];
    const float4 ev = *(const float4*)(embed + (long)tok*DIM + d0);
    int a0,a1,a2,a3,c0,c1v,c2v,c3;
    quant2(ev.x,a0,c0); quant2(ev.y,a1,c1v); quant2(ev.z,a2,c2v); quant2(ev.w,a3,c3);
    const int kc = 4 + (d0 >> 6);
    const int kk = d0 & 63;
    const int ee0 = (kk >> 4) << 2;
    const int lp  = ((kk >> 2) & 3)*16 + s2;
    const int off = kc*1024 + lp*16 + ee0;
    *(int*)(X1 + off) = pack4(a0,a1,a2,a3);
    *(int*)(X2 + off) = pack4(c0,c1v,c2v,c3);
  }
  __syncthreads();

  for (int t = 0; t < TW; ++t) {
    i32x4 p1r  = {0,0,0,0}, p23r  = {0,0,0,0};
    i32x4 p1z  = {0,0,0,0}, p23z  = {0,0,0,0};
    i32x4 p1nh = {0,0,0,0}, p23nh = {0,0,0,0};
    i32x4 p1nx = {0,0,0,0}, p23nx = {0,0,0,0};
    #pragma unroll
    for (int kc = 0; kc < 6; ++kc) {
      const i32x4 x1v = *(const i32x4*)(X1 + kc*1024 + lane*16);
      const i32x4 x2v = *(const i32x4*)(X2 + kc*1024 + lane*16);
      mfma3(W1, W2, ((long)(w*6      + kc))*1024 + lane*16, x1v, x2v, p1r, p23r);
      mfma3(W1, W2, ((long)((w+16)*6 + kc))*1024 + lane*16, x1v, x2v, p1z, p23z);
      if (kc < 4) mfma3(W1, W2, ((long)((w+32)*6 + kc))*1024 + lane*16, x1v, x2v, p1nh, p23nh);
      else        mfma3(W1, W2, ((long)((w+32)*6 + kc))*1024 + lane*16, x1v, x2v, p1nx, p23nx);
    }
    const float cc1 = SW_Q * SX_Q;
    const float cc2 = cc1 * (1.0f/256.0f);
    #pragma unroll
    for (int i = 0; i < 4; ++i) {
      float ar = fmaf(cc1, (float)p1r[i],  fmaf(cc2, (float)p23r[i],  b_r[i]));
      float az = fmaf(cc1, (float)p1z[i],  fmaf(cc2, (float)p23z[i],  b_z[i]));
      float ah = fmaf(cc1, (float)p1nh[i], fmaf(cc2, (float)p23nh[i], b_nh[i]));
      float ax = fmaf(cc1, (float)p1nx[i], fmaf(cc2, (float)p23nx[i], b_nx[i]));
      float rg = sigm(ar);
      float zg = sigm(az);
      float ng = tanhfast(ax + rg*ah);
      float hv = (1.0f - zg)*ng + zg*hold[i];
      hold[i] = hv;
      bool inm = dir ? (t >= TW - len_s) : (t < len_s);
      if (inm) rmax[i] = fmaxf(rmax[i], hv);
    }
    __syncthreads();   // all waves done reading X before overwrite
    {
      const int kcw = j0 >> 6;
      const int kk  = j0 & 63;
      const int ee0 = (kk >> 4) << 2;
      const int lp  = ((kk >> 2) & 3)*16 + s;
      const int off = kcw*1024 + lp*16 + ee0;
      int a0,a1,a2,a3,c0,c1v,c2v,c3;
      quant2(hold[0],a0,c0); quant2(hold[1],a1,c1v);
      quant2(hold[2],a2,c2v); quant2(hold[3],a3,c3);
      *(int*)(X1 + off) = pack4(a0,a1,a2,a3);
      *(int*)(X2 + off) = pack4(c0,c1v,c2v,c3);
    }
    if (t < TW-1 && tid < 512) {
      const int tx = dir ? (TW-2-t) : (t+1);
      const int s2 = tid >> 5;
      const int d0 = (tid & 31) * 4;
      const int tok = x[(n0 + s2)*TW + tx];
      const float4 ev = *(const float4*)(embed + (long)tok*DIM + d0);
      int a0,a1,a2,a3,c0,c1v,c2v,c3;
      quant2(ev.x,a0,c0); quant2(ev.y,a1,c1v); quant2(ev.z,a2,c2v); quant2(ev.w,a3,c3);
      const int kc = 4 + (d0 >> 6);
      const int kk = d0 & 63;
      const int ee0 = (kk >> 4) << 2;
      const int lp  = ((kk >> 2) & 3)*16 + s2;
      const int off = kc*1024 + lp*16 + ee0;
      *(int*)(X1 + off) = pack4(a0,a1,a2,a3);
      *(int*)(X2 + off) = pack4(c0,c1v,c2v,c3);
    }
    __syncthreads();
  }
  #pragma unroll
  for (int i = 0; i < 4; ++i) {
    float v = (len_s > 0) ? rmax[i] : 0.0f;
    sent_vec[(long)(n0+s)*(2*HID) + dir*HID + j0 + i] = v;
  }
}

// ---------------- sentence-level GRU via i8 MFMA (xg precomputed; B=16 docs/block) ----------------
// grid 8 = 4 doc-groups x 2 dirs; 1024 thr = 16 waves.
__global__ __launch_bounds__(1024, 4)
void k_sent_i8(const float* __restrict__ xg,
               const signed char* __restrict__ SW1f, const signed char* __restrict__ SW2f,
               const signed char* __restrict__ SW1b, const signed char* __restrict__ SW2b,
               const float* __restrict__ bh_f, const float* __restrict__ bh_b,
               const int* __restrict__ dlens, float* __restrict__ doc_vec)
{
  __shared__ __align__(16) signed char X1[4*1024];
  __shared__ __align__(16) signed char X2[4*1024];
  const int blk = blockIdx.x;
  const int dir = blk & 1;
  const int g   = blk >> 1;
  const int tid = threadIdx.x;
  const int w    = tid >> 6;
  const int lane = tid & 63;
  const int hi4  = lane >> 4;
  const int s    = lane & 15;
  const int j0   = w*16 + hi4*4;
  const int d    = g*16 + s;
  const signed char* W1 = dir ? SW1b : SW1f;
  const signed char* W2 = dir ? SW2b : SW2f;
  const float* bh = dir ? bh_b : bh_f;
  float b_r[4], b_z[4], b_nh[4];
  #pragma unroll
  for (int i = 0; i < 4; ++i) {
    b_r[i]  = bh[j0+i];
    b_z[i]  = bh[j0+i+256];
    b_nh[i] = bh[j0+i+512];
  }
  float hold[4] = {0.f,0.f,0.f,0.f};
  float rmax[4] = {-INFINITY,-INFINITY,-INFINITY,-INFINITY};
  const int len_d = dlens[d];
  ((int*)X1)[tid] = 0; ((int*)X2)[tid] = 0;   // 1024 ints each
  __syncthreads();

  for (int t = 0; t < LSENT; ++t) {
    const int row = dir ? (LSENT-1-t) : t;
    const float* xgr = xg + ((long)(d*LSENT + row))*1536 + dir*768;
    const float4 xr4 = *(const float4*)(xgr + j0);
    const float4 xz4 = *(const float4*)(xgr + 256 + j0);
    const float4 xn4 = *(const float4*)(xgr + 512 + j0);
    const float xr[4] = {xr4.x, xr4.y, xr4.z, xr4.w};
    const float xz[4] = {xz4.x, xz4.y, xz4.z, xz4.w};
    const float xn[4] = {xn4.x, xn4.y, xn4.z, xn4.w};
    i32x4 p1r = {0,0,0,0}, p23r = {0,0,0,0};
    i32x4 p1z = {0,0,0,0}, p23z = {0,0,0,0};
    i32x4 p1n = {0,0,0,0}, p23n = {0,0,0,0};
    #pragma unroll
    for (int kc = 0; kc < 4; ++kc) {
      const i32x4 x1v = *(const i32x4*)(X1 + kc*1024 + lane*16);
      const i32x4 x2v = *(const i32x4*)(X2 + kc*1024 + lane*16);
      mfma3(W1, W2, ((long)(w*4      + kc))*1024 + lane*16, x1v, x2v, p1r, p23r);
      mfma3(W1, W2, ((long)((w+16)*4 + kc))*1024 + lane*16, x1v, x2v, p1z, p23z);
      mfma3(W1, W2, ((long)((w+32)*4 + kc))*1024 + lane*16, x1v, x2v, p1n, p23n);
    }
    const float cc1 = SW_Q * SX_Q;
    const float cc2 = cc1 * (1.0f/256.0f);
    #pragma unroll
    for (int i = 0; i < 4; ++i) {
      float ar = xr[i] + fmaf(cc1, (float)p1r[i], fmaf(cc2, (float)p23r[i], b_r[i]));
      float az = xz[i] + fmaf(cc1, (float)p1z[i], fmaf(cc2, (float)p23z[i], b_z[i]));
      float ah =         fmaf(cc1, (float)p1n[i], fmaf(cc2, (float)p23n[i], b_nh[i]));
      float rg = sigm(ar);
      float zg = sigm(az);
      float ng = tanhfast(xn[i] + rg*ah);
      float hv = (1.0f - zg)*ng + zg*hold[i];
      hold[i] = hv;
      bool inm = dir ? (t >= LSENT - len_d) : (t < len_d);
      if (inm) rmax[i] = fmaxf(rmax[i], hv);
    }
    __syncthreads();
    {
      const int kcw = j0 >> 6;
      const int kk  = j0 & 63;
      const int ee0 = (kk >> 4) << 2;
      const int lp  = ((kk >> 2) & 3)*16 + s;
      const int off = kcw*1024 + lp*16 + ee0;
      int a0,a1,a2,a3,c0,c1v,c2v,c3;
      quant2(hold[0],a0,c0); quant2(hold[1],a1,c1v);
      quant2(hold[2],a2,c2v); quant2(hold[3],a3,c3);
      *(int*)(X1 + off) = pack4(a0,a1,a2,a3);
      *(int*)(X2 + off) = pack4(c0,c1v,c2v,c3);
    }
    __syncthreads();
  }
  #pragma unroll
  for (int i = 0; i < 4; ++i)
    doc_vec[(long)d*512 + dir*256 + j0 + i] = (len_d > 0) ? rmax[i] : 0.0f;
}

// ---------------- doc-level GRU via i8 MFMA (B=1 in col 0); grid 2 (dir) ----------------
__global__ __launch_bounds__(1024, 4)
void k_doc_i8(const float* __restrict__ xg,
              const signed char* __restrict__ DW1f, const signed char* __restrict__ DW2f,
              const signed char* __restrict__ DW1b, const signed char* __restrict__ DW2b,
              const float* __restrict__ bh_f, const float* __restrict__ bh_b,
              float* __restrict__ blog)
{
  __shared__ __align__(16) signed char X1[4*1024];
  __shared__ __align__(16) signed char X2[4*1024];
  const int dir = blockIdx.x;
  const int tid = threadIdx.x;
  const int w    = tid >> 6;
  const int lane = tid & 63;
  const int hi4  = lane >> 4;
  const int s    = lane & 15;
  const int j0   = w*16 + hi4*4;
  const signed char* W1 = dir ? DW1b : DW1f;
  const signed char* W2 = dir ? DW2b : DW2f;
  const float* bh = dir ? bh_b : bh_f;
  float b_r[4], b_z[4], b_nh[4];
  #pragma unroll
  for (int i = 0; i < 4; ++i) {
    b_r[i]  = bh[j0+i];
    b_z[i]  = bh[j0+i+256];
    b_nh[i] = bh[j0+i+512];
  }
  float hold[4] = {0.f,0.f,0.f,0.f};
  float rmax[4] = {-INFINITY,-INFINITY,-INFINITY,-INFINITY};
  ((int*)X1)[tid] = 0; ((int*)X2)[tid] = 0;
  __syncthreads();

  for (int t = 0; t < NDOC; ++t) {
    const int row = dir ? (NDOC-1-t) : t;
    const float* xgr = xg + (long)row*1536 + dir*768;
    const float4 xr4 = *(const float4*)(xgr + j0);
    const float4 xz4 = *(const float4*)(xgr + 256 + j0);
    const float4 xn4 = *(const float4*)(xgr + 512 + j0);
    const float xr[4] = {xr4.x, xr4.y, xr4.z, xr4.w};
    const float xz[4] = {xz4.x, xz4.y, xz4.z, xz4.w};
    const float xn[4] = {xn4.x, xn4.y, xn4.z, xn4.w};
    i32x4 p1r = {0,0,0,0}, p23r = {0,0,0,0};
    i32x4 p1z = {0,0,0,0}, p23z = {0,0,0,0};
    i32x4 p1n = {0,0,0,0}, p23n = {0,0,0,0};
    #pragma unroll
    for (int kc = 0; kc < 4; ++kc) {
      const i32x4 x1v = *(const i32x4*)(X1 + kc*1024 + lane*16);
      const i32x4 x2v = *(const i32x4*)(X2 + kc*1024 + lane*16);
      mfma3(W1, W2, ((long)(w*4      + kc))*1024 + lane*16, x1v, x2v, p1r, p23r);
      mfma3(W1, W2, ((long)((w+16)*4 + kc))*1024 + lane*16, x1v, x2v, p1z, p23z);
      mfma3(W1, W2, ((long)((w+32)*4 + kc))*1024 + lane*16, x1v, x2v, p1n, p23n);
    }
    const float cc1 = SW_Q * SX_Q;
    const float cc2 = cc1 * (1.0f/256.0f);
    #pragma unroll
    for (int i = 0; i < 4; ++i) {
      float ar = xr[i] + fmaf(cc1, (float)p1r[i], fmaf(cc2, (float)p23r[i], b_r[i]));
      float az = xz[i] + fmaf(cc1, (float)p1z[i], fmaf(cc2, (float)p23z[i], b_z[i]));
      float ah =         fmaf(cc1, (float)p1n[i], fmaf(cc2, (float)p23n[i], b_nh[i]));
      float rg = sigm(ar);
      float zg = sigm(az);
      float ng = tanhfast(xn[i] + rg*ah);
      float hv = (1.0f - zg)*ng + zg*hold[i];
      hold[i] = hv;
      rmax[i] = fmaxf(rmax[i], hv);
    }
    __syncthreads();
    if (s == 0) {
      const int kcw = j0 >> 6;
      const int kk  = j0 & 63;
      const int ee0 = (kk >> 4) << 2;
      const int lp  = ((kk >> 2) & 3)*16;   // s = 0
      const int off = kcw*1024 + lp*16 + ee0;
      int a0,a1,a2,a3,c0,c1v,c2v,c3;
      quant2(hold[0],a0,c0); quant2(hold[1],a1,c1v);
      quant2(hold[2],a2,c2v); quant2(hold[3],a3,c3);
      *(int*)(X1 + off) = pack4(a0,a1,a2,a3);
      *(int*)(X2 + off) = pack4(c0,c1v,c2v,c3);
    }
    __syncthreads();
  }
  if (s == 0) {
    #pragma unroll
    for (int i = 0; i < 4; ++i) blog[dir*256 + j0 + i] = rmax[i];
  }
}

// ---------------- input-gate GEMM: out[b, 0:768]=fwd gates, [768:1536]=bwd; Din=512 ----------------
__global__ __launch_bounds__(256)
void k_gates(const float* __restrict__ A,
             const float* __restrict__ W4f, const float* __restrict__ W4b,
             const float* __restrict__ bif, const float* __restrict__ bib,
             float* __restrict__ out)
{
  __shared__ __align__(16) float a_lds[8][512];
  const int r0 = blockIdx.x * 8;
  const int j  = threadIdx.x;
  #pragma unroll
  for (int q = 0; q < 4; ++q) {
    int fi = j + q*256;
    int rr = fi >> 7; int cc = (fi & 127) * 4;
    *(float4*)(&a_lds[rr][cc]) = *(const float4*)(A + (long)(r0+rr)*512 + cc);
  }
  __syncthreads();
  float acc[6][8];
  {
    float bias[6] = { bif[j], bif[j+256], bif[j+512], bib[j], bib[j+256], bib[j+512] };
    #pragma unroll
    for (int k = 0; k < 6; ++k)
      #pragma unroll
      for (int rr = 0; rr < 8; ++rr) acc[k][rr] = bias[k];
  }
  for (int d4 = 0; d4 < 128; ++d4) {
    float4 w0 = *(const float4*)(W4f + ((long)d4*G3 + j      )*4);
    float4 w1 = *(const float4*)(W4f + ((long)d4*G3 + j + 256)*4);
    float4 w2 = *(const float4*)(W4f + ((long)d4*G3 + j + 512)*4);
    float4 w3 = *(const float4*)(W4b + ((long)d4*G3 + j      )*4);
    float4 w4v= *(const float4*)(W4b + ((long)d4*G3 + j + 256)*4);
    float4 w5 = *(const float4*)(W4b + ((long)d4*G3 + j + 512)*4);
    #pragma unroll
    for (int rr = 0; rr < 8; ++rr){
      const float4 a4 = *(const float4*)(&a_lds[rr][d4*4]);
      fma4(acc[0][rr], w0, a4);
      fma4(acc[1][rr], w1, a4);
      fma4(acc[2][rr], w2, a4);
      fma4(acc[3][rr], w3, a4);
      fma4(acc[4][rr], w4v, a4);
      fma4(acc[5][rr], w5, a4);
    }
  }
  #pragma unroll
  for (int rr = 0; rr < 8; ++rr){
    long base = (long)(r0+rr)*1536;
    out[base + j      ] = acc[0][rr];
    out[base + j + 256] = acc[1][rr];
    out[base + j + 512] = acc[2][rr];
    out[base + j + 768] = acc[3][rr];
    out[base + j +1024] = acc[4][rr];
    out[base + j +1280] = acc[5][rr];
  }
}

// ---------------- scoring: content + salience + pos scores + bias ----------------
__global__ __launch_bounds__(256)
void k_score(const float* __restrict__ docs /*[2048,512]*/, const float* __restrict__ doc_vec,
             const float* __restrict__ blog, const float* __restrict__ W4sal,
             const float* __restrict__ w_content, const float* __restrict__ w_dpos,
             const float* __restrict__ w_spos, const float* __restrict__ doc_pos_tab,
             const float* __restrict__ sent_pos_tab, const float* __restrict__ sent_bias,
             const int* __restrict__ dlens, float* __restrict__ out)
{
  __shared__ __align__(16) float ctx[1024];
  __shared__ __align__(16) float cw[1024];   // [0:512) cproj, [512:1024) w_content
  const int n = blockIdx.x;
  const int j = threadIdx.x;
  ctx[j]       = blog[j];
  ctx[256 + j] = blog[256 + j];
  ctx[512 + j] = doc_vec[(long)n*512 + j];
  ctx[768 + j] = doc_vec[(long)n*512 + 256 + j];
  cw[512 + j]  = w_content[j];
  cw[768 + j]  = w_content[256 + j];
  __syncthreads();
  float acc0 = 0.0f, acc1 = 0.0f;
  for (int e4 = 0; e4 < 256; ++e4) {
    const float4 c4 = *(const float4*)(&ctx[e4*4]);
    const float4 w0 = *(const float4*)(W4sal + ((long)e4*512 + j      )*4);
    const float4 w1 = *(const float4*)(W4sal + ((long)e4*512 + j + 256)*4);
    fma4(acc0, w0, c4);
    fma4(acc1, w1, c4);
  }
  cw[j] = acc0; cw[j + 256] = acc1;
  __syncthreads();
  const int l = j >> 3, p = j & 7;
  const float* drow = docs + ((long)n*LSENT + l)*512;
  float pc = 0.0f, ps = 0.0f;
  for (int i = p*64; i < p*64 + 64; i += 4) {
    const float4 dv  = *(const float4*)(drow + i);
    const float4 wc4 = *(const float4*)(&cw[512 + i]);
    const float4 cp4 = *(const float4*)(&cw[i]);
    fma4(pc, dv, wc4);
    fma4(ps, dv, cp4);
  }
  #pragma unroll
  for (int o = 1; o < 8; o <<= 1) {
    pc += __shfl_xor(pc, o, 8);
    ps += __shfl_xor(ps, o, 8);
  }
  if (p == 0) {
    const int dlen = dlens[n];
    const int di = (n * PDOC) / NDOC;
    float ds = 0.0f;
    for (int i = 0; i < PDIMM; ++i) ds = fmaf(doc_pos_tab[(long)di*PDIMM + i], w_dpos[i], ds);
    const int safe = (dlen > 1) ? dlen : 1;
    int si = (l * PSENT) / safe;
    if (si > PSENT-1) si = PSENT-1;
    float ss = 0.0f;
    for (int i = 0; i < PDIMM; ++i) ss = fmaf(sent_pos_tab[(long)si*PDIMM + i], w_spos[i], ss);
    out[n*LSENT + l] = pc + ps + ds + ss + sent_bias[0];
  }
}

extern "C" void kernel_launch(void* const* d_in, const int* in_sizes, int n_in,
                              void* d_out, int out_size, void* d_ws, size_t ws_size,
                              hipStream_t stream)
{
  const int*   x        = (const int*)  d_in[0];
  const int*   doc_lens = (const int*)  d_in[1];
  const float* embed    = (const float*)d_in[2];
  const float* wWi_f = (const float*)d_in[3];
  const float* wWh_f = (const float*)d_in[4];
  const float* wbi_f = (const float*)d_in[5];
  const float* wbh_f = (const float*)d_in[6];
  const float* wWi_b = (const float*)d_in[7];
  const float* wWh_b = (const float*)d_in[8];
  const float* wbi_b = (const float*)d_in[9];
  const float* wbh_b = (const float*)d_in[10];
  const float* sWi_f = (const float*)d_in[11];
  const float* sWh_f = (const float*)d_in[12];
  const float* sbi_f = (const float*)d_in[13];
  const float* sbh_f = (const float*)d_in[14];
  const float* sWi_b = (const float*)d_in[15];
  const float* sWh_b = (const float*)d_in[16];
  const float* sbi_b = (const float*)d_in[17];
  const float* sbh_b = (const float*)d_in[18];
  const float* dWi_f = (const float*)d_in[19];
  const float* dWh_f = (const float*)d_in[20];
  const float* dbi_f = (const float*)d_in[21];
  const float* dbh_f = (const float*)d_in[22];
  const float* dWi_b = (const float*)d_in[23];
  const float* dWh_b = (const float*)d_in[24];
  const float* dbi_b = (const float*)d_in[25];
  const float* dbh_b = (const float*)d_in[26];
  const float* doc_pos_tab  = (const float*)d_in[27];
  const float* sent_pos_tab = (const float*)d_in[28];
  const float* w_content    = (const float*)d_in[29];
  const float* W_sal        = (const float*)d_in[30];
  const float* w_dpos       = (const float*)d_in[31];
  const float* w_spos       = (const float*)d_in[32];
  const float* sent_bias    = (const float*)d_in[33];

  float* ws = (float*)d_ws;
  signed char* wsb = (signed char*)d_ws;

  // i8 weight frags: word (6 kc, with Wi), sent/doc (4 kc, Wh only)
  PP pp;
  auto setp = [&](int i, const float* Wh, const float* Wi, long d1, long d2, long cnt, int nkc){
    pp.e[i].Wh = Wh; pp.e[i].Wi = Wi; pp.e[i].d1 = wsb + d1; pp.e[i].d2 = wsb + d2;
    pp.e[i].cnt = cnt; pp.e[i].nkc = nkc;
  };
  setp(0, wWh_f, wWi_f, OFFB_W1F,  OFFB_W2F,  294912, 6);
  setp(1, wWh_b, wWi_b, OFFB_W1B,  OFFB_W2B,  294912, 6);
  setp(2, sWh_f, sWh_f, OFFB_SW1F, OFFB_SW2F, 196608, 4);
  setp(3, sWh_b, sWh_b, OFFB_SW1B, OFFB_SW2B, 196608, 4);
  setp(4, dWh_f, dWh_f, OFFB_DW1F, OFFB_DW2F, 196608, 4);
  setp(5, dWh_b, dWh_b, OFFB_DW1B, OFFB_DW2B, 196608, 4);
  long ptotal = 2*294912 + 4*196608;   // 1,376,256
  k_prep<<<(int)((ptotal + 255)/256), 256, 0, stream>>>(pp, ptotal);

  // fp32 packed-4 transposes for sWi/dWi/salience
  TT tt;
  int idx = 0;
  auto add = [&](const float* src, long dst, int R, int Dk, int sh){
    tt.t[idx].src = src; tt.t[idx].dst = dst; tt.t[idx].cnt = (long)R*Dk;
    tt.t[idx].sh = sh; tt.t[idx].R = R; ++idx;
  };
  add(sWi_f, OFF_W4_sWi_f, 768, 512, 9);
  add(sWi_b, OFF_W4_sWi_b, 768, 512, 9);
  add(dWi_f, OFF_W4_dWi_f, 768, 512, 9);
  add(dWi_b, OFF_W4_dWi_b, 768, 512, 9);
  add(W_sal, OFF_W4_salT,  512, 1024, 10);
  long total = 0;
  for (int i = 0; i < 5; ++i) total += tt.t[i].cnt;   // 2,097,152
  k_transpose<<<(int)((total + 255)/256), 256, 0, stream>>>(tt, ws, total);
  k_lens<<<NSENT/256, 256, 0, stream>>>(x, (int*)(ws + OFF_LENS));

  k_word_i8<<<256, 1024, 0, stream>>>(x, embed,
      wsb + OFFB_W1F, wsb + OFFB_W2F, wsb + OFFB_W1B, wsb + OFFB_W2B,
      wbi_f, wbi_b, wbh_f, wbh_b,
      (const int*)(ws + OFF_LENS), ws + OFF_SENTVEC);

  k_gates<<<NSENT/8, 256, 0, stream>>>(ws + OFF_SENTVEC,
      ws + OFF_W4_sWi_f, ws + OFF_W4_sWi_b, sbi_f, sbi_b, ws + OFF_XGS);

  k_sent_i8<<<8, 1024, 0, stream>>>(ws + OFF_XGS,
      wsb + OFFB_SW1F, wsb + OFFB_SW2F, wsb + OFFB_SW1B, wsb + OFFB_SW2B,
      sbh_f, sbh_b, doc_lens, ws + OFF_DOCVEC);

  k_gates<<<NDOC/8, 256, 0, stream>>>(ws + OFF_DOCVEC,
      ws + OFF_W4_dWi_f, ws + OFF_W4_dWi_b, dbi_f, dbi_b, ws + OFF_XGD);

  k_doc_i8<<<2, 1024, 0, stream>>>(ws + OFF_XGD,
      wsb + OFFB_DW1F, wsb + OFFB_DW2F, wsb + OFFB_DW1B, wsb + OFFB_DW2B,
      dbh_f, dbh_b, ws + OFF_BLOG);

  k_score<<<NDOC, 256, 0, stream>>>(ws + OFF_SENTVEC, ws + OFF_DOCVEC, ws + OFF_BLOG,
      ws + OFF_W4_salT, w_content, w_dpos, w_spos,
      doc_pos_tab, sent_pos_tab, sent_bias, doc_lens, (float*)d_out);
}